// Round 14
// baseline (433.532 us; speedup 1.0000x reference)
//
#include <hip/hip_runtime.h>
#include <math.h>

// ---------------------------------------------------------------------------
// R14: non-UP convs -> mfma_f32_32x32x16_f16. Cycle audit (R13): convs were
// LDS-read-BW-bound (180 ds_read_b128/wave/cc ~= 11250cy vs 5590cy MFMA).
// 32x32 halves operand bytes/FLOP -> 72 reads/wave/cc. Weight/input layouts,
// staging, swizzle, barriers all unchanged; only fragment indices + epilogue
// mapping change (A: row=l&31,k=(l>>5)*8+e; C/D: col=l&31,
// row=(reg&3)+8*(reg>>2)+4*(l>>5)). conv_up (R13) + attention frozen.
// ws: [0]mbits | [1KB]sT | [4MB)zeros(4x4KB stripes at MBs) | [8MB)hcA | [40MB)wt
// ---------------------------------------------------------------------------

#define B_N 8
#define NGF 64
#define HC 128
#define WC 128
#define QN (HC*WC)        // 16384
#define NEF 256
#define SN 32
#define TEMP_INV (1.0f/0.7f)
#define BN_SC 0.99999500003749969f   // 1/sqrt(1+1e-5)
#define TOPK 24

typedef _Float16 f16;
typedef __attribute__((ext_vector_type(8))) _Float16 f16x8;
typedef __attribute__((ext_vector_type(4))) _Float16 f16x4;
typedef __attribute__((ext_vector_type(4))) float f32x4;
typedef __attribute__((ext_vector_type(16))) float f32x16;

__device__ __forceinline__ void gload16(const void* g, void* l) {
    __builtin_amdgcn_global_load_lds(
        (const __attribute__((address_space(1))) void*)g,
        (__attribute__((address_space(3))) void*)l,
        16, 0, 0);
}

// ---------------- mask prep + 4KB zero stripes at +{0..3}MB -----------------
__global__ void prep_mask_k(const void* __restrict__ mraw,
                            unsigned* __restrict__ mbits,
                            unsigned* __restrict__ zp) {
    __shared__ int mode;
    if (threadIdx.x == 0) {
        const unsigned* u = (const unsigned*)mraw;
        bool i32 = true, f32m = true;
        for (int i = 0; i < 64; ++i) {
            unsigned v = u[i];
            if (v > 1u) i32 = false;
            if (v != 0u && v != 0x3F800000u) f32m = false;
        }
        mode = i32 ? 0 : (f32m ? 1 : 2);
    }
    __syncthreads();
    int t = threadIdx.x;
    for (int i = t; i < 4 * 1056; i += 256) {
        int cc = i / 1056, w = i - cc * 1056;
        zp[cc * 262144 + w - 16] = 0u;
    }
    if (t < B_N) {
        unsigned bits = 0;
        for (int s = 0; s < SN; ++s) {
            int idx = t * SN + s;
            bool on;
            if (mode == 0)      on = ((const int*)mraw)[idx] != 0;
            else if (mode == 1) on = ((const float*)mraw)[idx] != 0.0f;
            else                on = ((const unsigned char*)mraw)[idx] != 0;
            if (on) bits |= (1u << s);
        }
        mbits[t] = bits;
    }
}

// ---------------- sourceT[b,o,s]: 64 blocks, thread=(o_local,s) -------------
__global__ __launch_bounds__(256) void source_t_k(
        const float* __restrict__ w_ctx, const float* __restrict__ word_embs,
        float* __restrict__ sT) {
    int b = blockIdx.x >> 3;
    int o = ((blockIdx.x & 7) << 3) + (threadIdx.x >> 5);
    int s = threadIdx.x & 31;
    const float* wrow = w_ctx + (size_t)o * NEF;
    const float* wb = word_embs + (size_t)b * NEF * SN + s;
    float acc = 0.0f;
    #pragma unroll 8
    for (int c = 0; c < NEF; ++c) acc += wrow[c] * wb[(size_t)c * SN];
    sT[((size_t)b * NGF + o) * SN + s] = acc;
}

// ---------------- attention: writes h_c granule-major NCHW8c ----------------
__global__ __launch_bounds__(256) void attention_k(
        const float* __restrict__ h_code, const float* __restrict__ sT,
        const unsigned* __restrict__ mbits,
        float* __restrict__ att_out,   // (B,S,Q) fp32
        f16* __restrict__ hc) {        // [b][16][QN][8]: g0..7 h, g8..15 wctx
    int r0 = blockIdx.x * 256;
    int b = r0 >> 14;
    __shared__ float st[NGF * SN];
    const float* stg = sT + (size_t)b * NGF * SN;
    for (int i = threadIdx.x; i < NGF * SN; i += 256) st[i] = stg[i];
    __syncthreads();
    int q = (r0 & (QN - 1)) + threadIdx.x;

    const float* hb = h_code + (size_t)b * NGF * QN + q;
    f16* hcb = hc + (size_t)b * QN * 128;

    float a[SN];
    #pragma unroll
    for (int s = 0; s < SN; ++s) a[s] = 0.0f;
    for (int g8 = 0; g8 < 8; ++g8) {
        f16x8 t;
        #pragma unroll
        for (int r = 0; r < 8; ++r) {
            float v = hb[(size_t)(g8 * 8 + r) * QN];
            t[r] = (f16)v;
            #pragma unroll
            for (int s = 0; s < SN; ++s) a[s] += v * st[(g8 * 8 + r) * SN + s];
        }
        *(f16x8*)(hcb + ((size_t)g8 * QN + q) * 8) = t;   // contiguous 16B/lane
    }
    unsigned mb = mbits[q & 7];       // reference tile quirk: mask row = q%8
    #pragma unroll
    for (int s = 0; s < SN; ++s)
        a[s] = ((mb >> s) & 1u) ? -INFINITY : a[s] * TEMP_INV;

    // top-k threshold via stable rank (24th largest incl. duplicates).
    float thr = -INFINITY;
    #pragma unroll
    for (int s = 0; s < SN; ++s) {
        int rank = 0;
        #pragma unroll
        for (int j = 0; j < SN; ++j)
            rank += (a[j] > a[s]) || (a[j] == a[s] && j < s);
        if (rank == TOPK - 1) thr = a[s];
    }
    float m = -INFINITY;
    #pragma unroll
    for (int s = 0; s < SN; ++s) {
        if (a[s] < thr) a[s] = -INFINITY;
        m = fmaxf(m, a[s]);
    }
    float p[SN];
    if (m == -INFINITY) {
        #pragma unroll
        for (int s = 0; s < SN; ++s) p[s] = 1.0f / SN;
    } else {
        float sum = 0.0f;
        #pragma unroll
        for (int s = 0; s < SN; ++s) { p[s] = __expf(a[s] - m); sum += p[s]; }
        float inv = 1.0f / sum;
        #pragma unroll
        for (int s = 0; s < SN; ++s) p[s] *= inv;
    }
    float* ao = att_out + (size_t)b * SN * QN + q;
    #pragma unroll
    for (int s = 0; s < SN; ++s) ao[(size_t)s * QN] = p[s];
    for (int g8 = 0; g8 < 8; ++g8) {
        f16x8 t;
        #pragma unroll
        for (int r = 0; r < 8; ++r) {
            float acc = 0.0f;
            #pragma unroll
            for (int s = 0; s < SN; ++s) acc += st[(g8 * 8 + r) * SN + s] * p[s];
            t[r] = (f16)acc;
        }
        *(f16x8*)(hcb + ((size_t)(8 + g8) * QN + q) * 8) = t;
    }
}

// ---------------- weight transform: OIHW fp32 -> [cb][cc][t][co'][g'][8] f16 -
__global__ __launch_bounds__(256) void wt_transform_k(
        const float* __restrict__ w, f16* __restrict__ wt,
        int total, int HALF /*0 = non-GLU*/) {
    int idx = blockIdx.x * 256 + threadIdx.x;
    if (idx >= total) return;
    int e   = idx & 7;
    int gp  = (idx >> 3) & 3;
    int cop = (idx >> 5) & 63;
    int u   = idx >> 11;
    int t   = u % 9;
    int v   = u / 9;
    int cc  = v & 3;
    int cb  = v >> 2;
    int g   = gp ^ ((cop >> 1) & 3);
    int ci  = cc * 32 + g * 8 + e;
    int co  = HALF ? (cop < 32 ? cb * 32 + cop : HALF + cb * 32 + (cop - 32))
                   : cb * 64 + cop;
    wt[idx] = (f16)w[((size_t)co * 128 + ci) * 9 + t];
}

// ---------------- UP weight transform: parity-collapsed 2x2 kernels --------
__global__ __launch_bounds__(256) void wt_up_transform_k(
        const float* __restrict__ w, f16* __restrict__ wt) {
    int idx = blockIdx.x * 256 + threadIdx.x;    // total 524288
    int e   = idx & 7;
    int gp  = (idx >> 3) & 3;
    int cop = (idx >> 5) & 63;
    int tap = (idx >> 11) & 3;
    int pw  = (idx >> 13) & 1;
    int cc  = (idx >> 14) & 3;
    int ph  = (idx >> 16) & 1;
    int cb  = (idx >> 17) & 1;
    int g   = gp ^ ((cop >> 1) & 3);
    int ci  = cc * 32 + g * 8 + e;
    int co  = cop < 32 ? cb * 32 + cop : 64 + cb * 32 + (cop - 32);
    int ra = tap >> 1, bb = tap & 1;
    const float* wp = w + ((size_t)co * 128 + ci) * 9;
    float acc = 0.0f;
    #pragma unroll
    for (int kh = 0; kh < 3; ++kh) {
        int rma = (ph == 0) ? (kh == 0 ? 0 : 1) : (kh == 2 ? 1 : 0);
        if (rma != ra) continue;
        #pragma unroll
        for (int kw = 0; kw < 3; ++kw) {
            int cma = (pw == 0) ? (kw == 0 ? 0 : 1) : (kw == 2 ? 1 : 0);
            if (cma == bb) acc += wp[kh * 3 + kw];
        }
    }
    wt[idx] = (f16)acc;
}

// ---------------- non-UP conv3x3: 512 thr, q-512 tile, 32x32x16 MFMA --------
// 8 waves = row lr(4) x col-half chf(2); per wave 64co' x 64q via 2m x 2n
// tiles of 32x32, 2 k-steps/cc/tap. 72 ds_read_b128 + 72 MFMA per wave per cc
// (was 180 reads / 144 MFMA at 16x16). Staging/layout/barriers = R11.
template<int COUT, bool GLU, bool RES>
__global__ __launch_bounds__(512) void conv_mfma_k(
        const f16* __restrict__ in, const f16* __restrict__ wt,
        const float* __restrict__ gamma, const float* __restrict__ beta,
        const f16* __restrict__ res, f16* __restrict__ outh,
        const char* __restrict__ zeros) {
    constexpr int HALF = COUT / 2;
    constexpr int OCH  = GLU ? HALF : COUT;
    constexpr int IBUF = 57344;               // 3584 granules (3120 real + pad)

    __shared__ char smem[2 * IBUF + 36864];
    char* wB = smem + 2 * IBUF;

    const int tid = threadIdx.x, lane = tid & 63, wv = tid >> 6;
    const int l31 = lane & 31, lg = lane >> 5;
    const int b = blockIdx.z, cb = blockIdx.y, qt = blockIdx.x;
    const int q0 = qt * 512;
    const int h0 = qt * 4;
    const int lr = wv >> 1, chf = wv & 1;

    f32x16 acc[2][2];
    #pragma unroll
    for (int m = 0; m < 2; ++m)
        #pragma unroll
        for (int n = 0; n < 2; ++n)
            #pragma unroll
            for (int r = 0; r < 16; ++r) acc[m][n][r] = 0.0f;

    const f16* inb = in + (size_t)b * QN * 128;
    const char* wtb = (const char*)wt + (size_t)cb * 147456;

    const char* srcK[7];
    #pragma unroll
    for (int k = 0; k < 7; ++k) {
        int idx = (k << 9) + tid;
        int r = idx / 520;
        int rem = idx - r * 520;
        int wi = rem >> 2, gp = rem & 3;
        int g = gp ^ ((wi >> 1) & 3);
        int gh = h0 - 1 + r;
        int gw = wi - 1;
        const char* s = zeros;
        if (r < 6 && (unsigned)gh < (unsigned)HC && (unsigned)gw < (unsigned)WC)
            s = (const char*)(inb + (((size_t)g * QN + (size_t)gh * WC + gw) << 3));
        srcK[k] = s;
    }
    const int dstB = (tid & 448) << 4;

    auto stage_in = [&](int cc, int buf) {
        char* base = smem + buf * IBUF;
        #pragma unroll
        for (int k = 0; k < 7; ++k)
            gload16(srcK[k] + (cc << 20), base + (k << 13) + dstB);
    };
    auto stage_w = [&](int cc) {
        const char* wsrc = wtb + cc * 36864 + (tid << 4);
        #pragma unroll
        for (int k = 0; k < 4; ++k)
            gload16(wsrc + (k << 13), wB + (k << 13) + dstB);
        if (tid < 256)
            gload16(wsrc + (4 << 13), wB + (4 << 13) + dstB);
    };

    stage_in(0, 0);
    stage_w(0);
    __syncthreads();
    for (int cc = 0; cc < 4; ++cc) {
        if (cc < 3) stage_in(cc + 1, (cc + 1) & 1);   // hides under compute
        const char* bb = smem + (cc & 1) * IBUF;

        #pragma unroll
        for (int t = 0; t < 9; ++t) {
            const int kh = t / 3, kw = t % 3;
            f16x8 af[2][2], bf[2][2];          // [kk][tile]
            #pragma unroll
            for (int kk = 0; kk < 2; ++kk) {
                const int slot = kk * 2 + lg;  // ci granule within cc
                #pragma unroll
                for (int m = 0; m < 2; ++m) {
                    int co = m * 32 + l31;
                    af[kk][m] = *(const f16x8*)(wB + (t << 12) + (co << 6)
                                + ((slot ^ ((co >> 1) & 3)) << 4));
                }
                #pragma unroll
                for (int n = 0; n < 2; ++n) {
                    int wi = chf * 64 + n * 32 + l31 + kw;
                    int off = (lr + kh) * 8320 + wi * 64
                              + ((slot ^ ((wi >> 1) & 3)) << 4);
                    bf[kk][n] = *(const f16x8*)(bb + off);
                }
            }
            #pragma unroll
            for (int kk = 0; kk < 2; ++kk)
                #pragma unroll
                for (int m = 0; m < 2; ++m)
                    #pragma unroll
                    for (int n = 0; n < 2; ++n)
                        acc[m][n] = __builtin_amdgcn_mfma_f32_32x32x16_f16(
                            af[kk][m], bf[kk][n], acc[m][n], 0, 0, 0);
        }
        __syncthreads();                      // drains input prefetch (hidden)
        if (cc < 3) {
            stage_w(cc + 1);                  // 36.9KB L2-hot refill
            __syncthreads();
        }
    }

    // ---- epilogue: C/D col=l31 (q), row=(reg&3)+8*(reg>>2)+4*lg (co) ------
    const int qb = lr * 128 + chf * 64;
    if (GLU) {
        #pragma unroll
        for (int n = 0; n < 2; ++n) {
            const int q = q0 + qb + n * 32 + l31;
            #pragma unroll
            for (int rg = 0; rg < 4; ++rg) {
                const int co = cb * 32 + rg * 8 + 4 * lg;   // value channel base
                float s1[4], o1[4], s2[4], o2[4];
                #pragma unroll
                for (int r = 0; r < 4; ++r) {
                    s1[r] = gamma[co + r] * BN_SC;        o1[r] = beta[co + r];
                    s2[r] = gamma[co + r + HALF] * BN_SC; o2[r] = beta[co + r + HALF];
                }
                f16x4 tv;
                #pragma unroll
                for (int r = 0; r < 4; ++r) {
                    float yv = acc[0][n][rg * 4 + r] * s1[r] + o1[r];
                    float zv = acc[1][n][rg * 4 + r] * s2[r] + o2[r];
                    tv[r] = (f16)(yv / (1.0f + __expf(-zv)));
                }
                *(f16x4*)(outh + ((((size_t)b * (OCH / 8) + (co >> 3)) << 14)
                                  + q) * 8 + (co & 7)) = tv;
            }
        }
    } else {
        #pragma unroll
        for (int m = 0; m < 2; ++m) {
            #pragma unroll
            for (int n = 0; n < 2; ++n) {
                const int q = q0 + qb + n * 32 + l31;
                #pragma unroll
                for (int rg = 0; rg < 4; ++rg) {
                    const int c0 = cb * 64 + m * 32 + rg * 8 + 4 * lg;
                    const size_t gaddr = ((((size_t)b * 16 + (c0 >> 3)) << 14) + q) * 8 + (c0 & 7);
                    float s[4], o[4], ov[4];
                    #pragma unroll
                    for (int r = 0; r < 4; ++r) {
                        s[r] = gamma[c0 + r] * BN_SC; o[r] = beta[c0 + r];
                        ov[r] = acc[m][n][rg * 4 + r] * s[r] + o[r];
                    }
                    if (RES) {
                        f16x4 rv = *(const f16x4*)(res + gaddr);
                        #pragma unroll
                        for (int r = 0; r < 4; ++r) ov[r] += (float)rv[r];
                    }
                    f16x4 tv;
                    #pragma unroll
                    for (int r = 0; r < 4; ++r) tv[r] = (f16)ov[r];
                    *(f16x4*)(outh + gaddr) = tv;
                }
            }
        }
    }
}

// ---------------- UP conv (R13): barrier-free K-loop, bf direct glb->VGPR ---
__global__ __launch_bounds__(512, 2) void conv_up_k(
        const f16* __restrict__ in, const f16* __restrict__ wt,
        const float* __restrict__ gamma, const float* __restrict__ beta,
        float* __restrict__ outf, const char* __restrict__ zeros) {
    __shared__ char wL[131072];

    const int tid = threadIdx.x, lane = tid & 63, wv = tid >> 6;
    const int l15 = lane & 15, kg = lane >> 4;
    const int b = blockIdx.z, cb = blockIdx.y;
    const int j = blockIdx.x >> 1, ph = blockIdx.x & 1;
    const int rr = wv >> 1;                   // output row 0..3
    const int p  = wv & 1;                    // output col parity

    const char* wtb = (const char*)wt + (size_t)(cb * 2 + ph) * 131072;
    const int dstB = (tid & 448) << 4;
    #pragma unroll
    for (int k = 0; k < 16; ++k)
        gload16(wtb + (((k << 9) + tid) << 4), wL + (k << 13) + dstB);
    __syncthreads();

    f32x4 acc[4][8];
    #pragma unroll
    for (int m = 0; m < 4; ++m)
        #pragma unroll
        for (int n = 0; n < 8; ++n) acc[m][n] = (f32x4){0.f, 0.f, 0.f, 0.f};

    const char* inbB = (const char*)in + (size_t)b * QN * 256;  // 16 planes
    const int colb = (l15 + p - 1) << 4;
    const char* rp0;
    const char* rp1;
    {
        int r0 = 4 * j - 1 + ph + rr;
        int r1 = r0 + 1;
        rp0 = ((unsigned)r0 < 128u)
            ? inbB + (((size_t)kg * QN + (size_t)r0 * 128) << 4) + colb
            : zeros + 16 + colb;
        rp1 = ((unsigned)r1 < 128u)
            ? inbB + (((size_t)kg * QN + (size_t)r1 * 128) << 4) + colb
            : zeros + 16 + colb;
    }

    auto LG = [&](f16x8 (&bf)[8], int cc, int t) {
        const int sh_ = t & 1;
        const char* bl = ((t >> 1) ? rp1 : rp0) + (cc << 20) + (sh_ << 4);
        #pragma unroll
        for (int n = 0; n < 8; ++n) {
            if (n == 0 || n == 7) {
                int sc = (n << 4) + l15 + sh_ + p - 1;
                const char* a = ((unsigned)sc < 128u)
                    ? (bl + n * 256)
                    : (zeros + (cc << 20) + 16 + sc * 16);
                bf[n] = *(const f16x8*)a;
            } else {
                bf[n] = *(const f16x8*)(bl + n * 256);
            }
        }
    };
    auto CP = [&](f16x8 (&bf)[8], int cc, int t) {
        f16x8 af[4];
        const int tb = cc * 32768 + ((p * 4 + t) << 12);
        #pragma unroll
        for (int m = 0; m < 4; ++m) {
            int co = m * 16 + l15;
            af[m] = *(const f16x8*)(wL + tb + (co << 6)
                                    + ((kg ^ ((co >> 1) & 3)) << 4));
        }
        #pragma unroll
        for (int m = 0; m < 4; ++m)
            #pragma unroll
            for (int n = 0; n < 8; ++n)
                acc[m][n] = __builtin_amdgcn_mfma_f32_16x16x32_f16(af[m], bf[n], acc[m][n], 0, 0, 0);
    };

    f16x8 bfA[8], bfB[8];
    LG(bfA, 0, 0);
    #pragma unroll
    for (int k = 0; k < 16; ++k) {
        const int cc = k >> 2, t = k & 3;
        const int k1 = k + 1;
        if ((k & 1) == 0) {
            if (k1 < 16) LG(bfB, k1 >> 2, k1 & 3);
            CP(bfA, cc, t);
        } else {
            if (k1 < 16) LG(bfA, k1 >> 2, k1 & 3);
            CP(bfB, cc, t);
        }
    }

    // ---- epilogue: BN + GLU -> fp32 NCHW ----
    const int r4 = kg * 4;
    const int h = 8 * j + 2 * rr + ph;
    #pragma unroll
    for (int mv = 0; mv < 2; ++mv) {
        const int v0 = cb * 32 + mv * 16 + r4;
        float s1[4], o1[4], s2[4], o2[4];
        #pragma unroll
        for (int r = 0; r < 4; ++r) {
            s1[r] = gamma[v0 + r] * BN_SC;      o1[r] = beta[v0 + r];
            s2[r] = gamma[v0 + r + 64] * BN_SC; o2[r] = beta[v0 + r + 64];
        }
        #pragma unroll
        for (int n = 0; n < 8; ++n) {
            const int w = 2 * ((n << 4) + l15) + p;
            float ov[4];
            #pragma unroll
            for (int r = 0; r < 4; ++r) {
                float yv = acc[mv][n][r] * s1[r] + o1[r];
                float zv = acc[mv + 2][n][r] * s2[r] + o2[r];
                ov[r] = yv / (1.0f + __expf(-zv));
            }
            #pragma unroll
            for (int r = 0; r < 4; ++r)
                outf[(((size_t)b * 64 + v0 + r) * 256 + h) * 256 + w] = ov[r];
        }
    }
}

// ---------------------------------------------------------------------------
extern "C" void kernel_launch(void* const* d_in, const int* in_sizes, int n_in,
                              void* d_out, int out_size, void* d_ws, size_t ws_size,
                              hipStream_t stream) {
    (void)in_sizes; (void)n_in; (void)out_size; (void)ws_size;
    const float* h_code    = (const float*)d_in[0];
    const float* word_embs = (const float*)d_in[2];
    const void*  mask      = d_in[3];
    const float* w_ctx     = (const float*)d_in[4];
    const float* r0_w1 = (const float*)d_in[5];
    const float* r0_g1 = (const float*)d_in[6];
    const float* r0_b1 = (const float*)d_in[7];
    const float* r0_w2 = (const float*)d_in[8];
    const float* r0_g2 = (const float*)d_in[9];
    const float* r0_b2 = (const float*)d_in[10];
    const float* r1_w1 = (const float*)d_in[11];
    const float* r1_g1 = (const float*)d_in[12];
    const float* r1_b1 = (const float*)d_in[13];
    const float* r1_w2 = (const float*)d_in[14];
    const float* r1_g2 = (const float*)d_in[15];
    const float* r1_b2 = (const float*)d_in[16];
    const float* up_w  = (const float*)d_in[17];
    const float* up_g  = (const float*)d_in[18];
    const float* up_b  = (const float*)d_in[19];

    float* outp = (float*)d_out;                         // (8,64,256,256) fp32
    float* attp = outp + (size_t)B_N * NGF * 4 * HC * WC;

    unsigned* mbits = (unsigned*)d_ws;
    float* sT  = (float*)((char*)d_ws + 1024);
    char* zeros = (char*)d_ws + ((size_t)4 << 20);                 // 4x4KB stripes
    f16* hcA   = (f16*)((char*)d_ws + ((size_t)8 << 20));          // 32MB
    f16* wtbuf = (f16*)((char*)d_ws + ((size_t)40 << 20));         // ~3MB

    const int W1_TOT = 4 * 4 * 9 * 64 * 32;   // 294912 (GLU 256-out)
    const int W2_TOT = 2 * 4 * 9 * 64 * 32;   // 147456
    const int WUP_TOT = 2 * 2 * 4 * 2 * 4 * 64 * 32;   // 524288 (parity 2x2)
    f16* Wr0c1 = wtbuf;
    f16* Wr0c2 = Wr0c1 + W1_TOT;
    f16* Wr1c1 = Wr0c2 + W2_TOT;
    f16* Wr1c2 = Wr1c1 + W1_TOT;
    f16* Wup   = Wr1c2 + W2_TOT;

    f16* Bbuf = (f16*)d_out;                               // [0,32MB)
    f16* Cbuf = (f16*)((char*)d_out + ((size_t)32 << 20)); // [32,64MB)

    prep_mask_k<<<1, 256, 0, stream>>>(mask, mbits, (unsigned*)zeros);
    source_t_k<<<64, 256, 0, stream>>>(w_ctx, word_embs, sT);

    wt_transform_k<<<(W1_TOT + 255) / 256, 256, 0, stream>>>(r0_w1, Wr0c1, W1_TOT, 128);
    wt_transform_k<<<(W2_TOT + 255) / 256, 256, 0, stream>>>(r0_w2, Wr0c2, W2_TOT, 0);
    wt_transform_k<<<(W1_TOT + 255) / 256, 256, 0, stream>>>(r1_w1, Wr1c1, W1_TOT, 128);
    wt_transform_k<<<(W2_TOT + 255) / 256, 256, 0, stream>>>(r1_w2, Wr1c2, W2_TOT, 0);
    wt_up_transform_k<<<WUP_TOT / 256, 256, 0, stream>>>(up_w, Wup);

    attention_k<<<(B_N * QN) / 256, 256, 0, stream>>>(h_code, sT, mbits, attp, hcA);

    // r0: conv1+GLU (hcA->B), conv2+res hcA (B->C)
    conv_mfma_k<256, true,  false>
        <<<dim3(32, 4, B_N), 512, 0, stream>>>(hcA, Wr0c1, r0_g1, r0_b1, nullptr, Bbuf, zeros);
    conv_mfma_k<128, false, true>
        <<<dim3(32, 2, B_N), 512, 0, stream>>>(Bbuf, Wr0c2, r0_g2, r0_b2, hcA, Cbuf, zeros);
    // r1: conv1+GLU (C->B), conv2+res C (B->hcA)
    conv_mfma_k<256, true,  false>
        <<<dim3(32, 4, B_N), 512, 0, stream>>>(Cbuf, Wr1c1, r1_g1, r1_b1, nullptr, Bbuf, zeros);
    conv_mfma_k<128, false, true>
        <<<dim3(32, 2, B_N), 512, 0, stream>>>(Bbuf, Wr1c2, r1_g2, r1_b2, Cbuf, hcA, zeros);
    // upsample2x + conv + GLU -> final fp32 NCHW (R13 barrier-free)
    conv_up_k<<<dim3(64, 2, B_N), 512, 0, stream>>>(hcA, Wup, up_g, up_b, outp, zeros);
}

// Round 15
// 418.668 us; speedup vs baseline: 1.0355x; 1.0355x over previous
//
#include <hip/hip_runtime.h>
#include <math.h>

// ---------------------------------------------------------------------------
// R15: (a) revert R14's 32x32 MFMA (4-way bank conflicts, no gain) -> R11's
// 16x16 non-UP convs; keep R13 barrier-free conv_up. (b) NEW: XCD-pinned
// block remap: all conv/attention grids 1D with b = wg&7 -> batch b's blocks
// land on XCD b (round-robin heuristic), making each XCD's 4MB b-slice
// L2-resident across cb-rounds (L3->L2 for 3/4 of conv fetches).
// ws: [0]mbits | [1KB]sT | [4MB)zeros(4x4KB stripes at MBs) | [8MB)hcA | [40MB)wt
// ---------------------------------------------------------------------------

#define B_N 8
#define NGF 64
#define HC 128
#define WC 128
#define QN (HC*WC)        // 16384
#define NEF 256
#define SN 32
#define TEMP_INV (1.0f/0.7f)
#define BN_SC 0.99999500003749969f   // 1/sqrt(1+1e-5)
#define TOPK 24

typedef _Float16 f16;
typedef __attribute__((ext_vector_type(8))) _Float16 f16x8;
typedef __attribute__((ext_vector_type(4))) _Float16 f16x4;
typedef __attribute__((ext_vector_type(4))) float f32x4;

__device__ __forceinline__ void gload16(const void* g, void* l) {
    __builtin_amdgcn_global_load_lds(
        (const __attribute__((address_space(1))) void*)g,
        (__attribute__((address_space(3))) void*)l,
        16, 0, 0);
}

// ---------------- mask prep + 4KB zero stripes at +{0..3}MB -----------------
__global__ void prep_mask_k(const void* __restrict__ mraw,
                            unsigned* __restrict__ mbits,
                            unsigned* __restrict__ zp) {
    __shared__ int mode;
    if (threadIdx.x == 0) {
        const unsigned* u = (const unsigned*)mraw;
        bool i32 = true, f32m = true;
        for (int i = 0; i < 64; ++i) {
            unsigned v = u[i];
            if (v > 1u) i32 = false;
            if (v != 0u && v != 0x3F800000u) f32m = false;
        }
        mode = i32 ? 0 : (f32m ? 1 : 2);
    }
    __syncthreads();
    int t = threadIdx.x;
    for (int i = t; i < 4 * 1056; i += 256) {
        int cc = i / 1056, w = i - cc * 1056;
        zp[cc * 262144 + w - 16] = 0u;
    }
    if (t < B_N) {
        unsigned bits = 0;
        for (int s = 0; s < SN; ++s) {
            int idx = t * SN + s;
            bool on;
            if (mode == 0)      on = ((const int*)mraw)[idx] != 0;
            else if (mode == 1) on = ((const float*)mraw)[idx] != 0.0f;
            else                on = ((const unsigned char*)mraw)[idx] != 0;
            if (on) bits |= (1u << s);
        }
        mbits[t] = bits;
    }
}

// ---------------- sourceT[b,o,s]: 64 blocks, thread=(o_local,s) -------------
__global__ __launch_bounds__(256) void source_t_k(
        const float* __restrict__ w_ctx, const float* __restrict__ word_embs,
        float* __restrict__ sT) {
    int b = blockIdx.x >> 3;
    int o = ((blockIdx.x & 7) << 3) + (threadIdx.x >> 5);
    int s = threadIdx.x & 31;
    const float* wrow = w_ctx + (size_t)o * NEF;
    const float* wb = word_embs + (size_t)b * NEF * SN + s;
    float acc = 0.0f;
    #pragma unroll 8
    for (int c = 0; c < NEF; ++c) acc += wrow[c] * wb[(size_t)c * SN];
    sT[((size_t)b * NGF + o) * SN + s] = acc;
}

// ---------------- attention: XCD-pinned (b = wg&7), NCHW8c output -----------
__global__ __launch_bounds__(256) void attention_k(
        const float* __restrict__ h_code, const float* __restrict__ sT,
        const unsigned* __restrict__ mbits,
        float* __restrict__ att_out,   // (B,S,Q) fp32
        f16* __restrict__ hc) {        // [b][16][QN][8]: g0..7 h, g8..15 wctx
    const int wg = blockIdx.x;
    const int b = wg & 7;
    const int qc0 = (wg >> 3) << 8;
    __shared__ float st[NGF * SN];
    const float* stg = sT + (size_t)b * NGF * SN;
    for (int i = threadIdx.x; i < NGF * SN; i += 256) st[i] = stg[i];
    __syncthreads();
    int q = qc0 + threadIdx.x;

    const float* hb = h_code + (size_t)b * NGF * QN + q;
    f16* hcb = hc + (size_t)b * QN * 128;

    float a[SN];
    #pragma unroll
    for (int s = 0; s < SN; ++s) a[s] = 0.0f;
    for (int g8 = 0; g8 < 8; ++g8) {
        f16x8 t;
        #pragma unroll
        for (int r = 0; r < 8; ++r) {
            float v = hb[(size_t)(g8 * 8 + r) * QN];
            t[r] = (f16)v;
            #pragma unroll
            for (int s = 0; s < SN; ++s) a[s] += v * st[(g8 * 8 + r) * SN + s];
        }
        *(f16x8*)(hcb + ((size_t)g8 * QN + q) * 8) = t;   // contiguous 16B/lane
    }
    unsigned mb = mbits[q & 7];       // reference tile quirk: mask row = q%8
    #pragma unroll
    for (int s = 0; s < SN; ++s)
        a[s] = ((mb >> s) & 1u) ? -INFINITY : a[s] * TEMP_INV;

    // top-k threshold via stable rank (24th largest incl. duplicates).
    float thr = -INFINITY;
    #pragma unroll
    for (int s = 0; s < SN; ++s) {
        int rank = 0;
        #pragma unroll
        for (int j = 0; j < SN; ++j)
            rank += (a[j] > a[s]) || (a[j] == a[s] && j < s);
        if (rank == TOPK - 1) thr = a[s];
    }
    float m = -INFINITY;
    #pragma unroll
    for (int s = 0; s < SN; ++s) {
        if (a[s] < thr) a[s] = -INFINITY;
        m = fmaxf(m, a[s]);
    }
    float p[SN];
    if (m == -INFINITY) {
        #pragma unroll
        for (int s = 0; s < SN; ++s) p[s] = 1.0f / SN;
    } else {
        float sum = 0.0f;
        #pragma unroll
        for (int s = 0; s < SN; ++s) { p[s] = __expf(a[s] - m); sum += p[s]; }
        float inv = 1.0f / sum;
        #pragma unroll
        for (int s = 0; s < SN; ++s) p[s] *= inv;
    }
    float* ao = att_out + (size_t)b * SN * QN + q;
    #pragma unroll
    for (int s = 0; s < SN; ++s) ao[(size_t)s * QN] = p[s];
    for (int g8 = 0; g8 < 8; ++g8) {
        f16x8 t;
        #pragma unroll
        for (int r = 0; r < 8; ++r) {
            float acc = 0.0f;
            #pragma unroll
            for (int s = 0; s < SN; ++s) acc += st[(g8 * 8 + r) * SN + s] * p[s];
            t[r] = (f16)acc;
        }
        *(f16x8*)(hcb + ((size_t)(8 + g8) * QN + q) * 8) = t;
    }
}

// ---------------- weight transform: OIHW fp32 -> [cb][cc][t][co'][g'][8] f16 -
__global__ __launch_bounds__(256) void wt_transform_k(
        const float* __restrict__ w, f16* __restrict__ wt,
        int total, int HALF /*0 = non-GLU*/) {
    int idx = blockIdx.x * 256 + threadIdx.x;
    if (idx >= total) return;
    int e   = idx & 7;
    int gp  = (idx >> 3) & 3;
    int cop = (idx >> 5) & 63;
    int u   = idx >> 11;
    int t   = u % 9;
    int v   = u / 9;
    int cc  = v & 3;
    int cb  = v >> 2;
    int g   = gp ^ ((cop >> 1) & 3);
    int ci  = cc * 32 + g * 8 + e;
    int co  = HALF ? (cop < 32 ? cb * 32 + cop : HALF + cb * 32 + (cop - 32))
                   : cb * 64 + cop;
    wt[idx] = (f16)w[((size_t)co * 128 + ci) * 9 + t];
}

// ---------------- UP weight transform: parity-collapsed 2x2 kernels --------
__global__ __launch_bounds__(256) void wt_up_transform_k(
        const float* __restrict__ w, f16* __restrict__ wt) {
    int idx = blockIdx.x * 256 + threadIdx.x;    // total 524288
    int e   = idx & 7;
    int gp  = (idx >> 3) & 3;
    int cop = (idx >> 5) & 63;
    int tap = (idx >> 11) & 3;
    int pw  = (idx >> 13) & 1;
    int cc  = (idx >> 14) & 3;
    int ph  = (idx >> 16) & 1;
    int cb  = (idx >> 17) & 1;
    int g   = gp ^ ((cop >> 1) & 3);
    int ci  = cc * 32 + g * 8 + e;
    int co  = cop < 32 ? cb * 32 + cop : 64 + cb * 32 + (cop - 32);
    int ra = tap >> 1, bb = tap & 1;
    const float* wp = w + ((size_t)co * 128 + ci) * 9;
    float acc = 0.0f;
    #pragma unroll
    for (int kh = 0; kh < 3; ++kh) {
        int rma = (ph == 0) ? (kh == 0 ? 0 : 1) : (kh == 2 ? 1 : 0);
        if (rma != ra) continue;
        #pragma unroll
        for (int kw = 0; kw < 3; ++kw) {
            int cma = (pw == 0) ? (kw == 0 ? 0 : 1) : (kw == 2 ? 1 : 0);
            if (cma == bb) acc += wp[kh * 3 + kw];
        }
    }
    wt[idx] = (f16)acc;
}

// ---------------- non-UP conv3x3: 512 thr, q-512, 16x16, XCD-pinned ---------
// 1D grid: wg -> b = wg&7 (XCD pin), pos = wg>>3, cb = pos>>5, qt = pos&31.
template<int COUT, bool GLU, bool RES>
__global__ __launch_bounds__(512) void conv_mfma_k(
        const f16* __restrict__ in, const f16* __restrict__ wt,
        const float* __restrict__ gamma, const float* __restrict__ beta,
        const f16* __restrict__ res, f16* __restrict__ outh,
        const char* __restrict__ zeros) {
    constexpr int HALF = COUT / 2;
    constexpr int OCH  = GLU ? HALF : COUT;
    constexpr int IBUF = 57344;               // 3584 granules (3120 real + pad)

    __shared__ char smem[2 * IBUF + 36864];
    char* wB = smem + 2 * IBUF;

    const int tid = threadIdx.x, lane = tid & 63, wv = tid >> 6;
    const int l15 = lane & 15, kg = lane >> 4;
    const int wg = blockIdx.x;
    const int b = wg & 7;
    const int pos = wg >> 3;
    const int cb = pos >> 5, qt = pos & 31;
    const int q0 = qt * 512;
    const int h0 = qt * 4;
    const int lr = wv >> 1, chf = wv & 1;

    f32x4 acc[4][4];
    #pragma unroll
    for (int m = 0; m < 4; ++m)
        #pragma unroll
        for (int n = 0; n < 4; ++n) acc[m][n] = (f32x4){0.f, 0.f, 0.f, 0.f};

    const f16* inb = in + (size_t)b * QN * 128;
    const char* wtb = (const char*)wt + (size_t)cb * 147456;

    const char* srcK[7];
    #pragma unroll
    for (int k = 0; k < 7; ++k) {
        int idx = (k << 9) + tid;
        int r = idx / 520;
        int rem = idx - r * 520;
        int wi = rem >> 2, gp = rem & 3;
        int g = gp ^ ((wi >> 1) & 3);
        int gh = h0 - 1 + r;
        int gw = wi - 1;
        const char* s = zeros;
        if (r < 6 && (unsigned)gh < (unsigned)HC && (unsigned)gw < (unsigned)WC)
            s = (const char*)(inb + (((size_t)g * QN + (size_t)gh * WC + gw) << 3));
        srcK[k] = s;
    }
    const int dstB = (tid & 448) << 4;

    auto stage_in = [&](int cc, int buf) {
        char* base = smem + buf * IBUF;
        #pragma unroll
        for (int k = 0; k < 7; ++k)
            gload16(srcK[k] + (cc << 20), base + (k << 13) + dstB);
    };
    auto stage_w = [&](int cc) {
        const char* wsrc = wtb + cc * 36864 + (tid << 4);
        #pragma unroll
        for (int k = 0; k < 4; ++k)
            gload16(wsrc + (k << 13), wB + (k << 13) + dstB);
        if (tid < 256)
            gload16(wsrc + (4 << 13), wB + (4 << 13) + dstB);
    };

    stage_in(0, 0);
    stage_w(0);
    __syncthreads();
    for (int cc = 0; cc < 4; ++cc) {
        if (cc < 3) stage_in(cc + 1, (cc + 1) & 1);   // hides under compute
        const char* bb = smem + (cc & 1) * IBUF;

        #pragma unroll
        for (int t = 0; t < 9; ++t) {
            const int kh = t / 3, kw = t % 3;
            f16x8 af[4], bf[4];
            #pragma unroll
            for (int m = 0; m < 4; ++m) {
                int co = m * 16 + l15;
                af[m] = *(const f16x8*)(wB + (t << 12) + (co << 6)
                                        + ((kg ^ ((co >> 1) & 3)) << 4));
            }
            #pragma unroll
            for (int n = 0; n < 4; ++n) {
                int wi = chf * 64 + (n << 4) + l15 + kw;
                int off = (lr + kh) * 8320 + wi * 64 + ((kg ^ ((wi >> 1) & 3)) << 4);
                bf[n] = *(const f16x8*)(bb + off);
            }
            #pragma unroll
            for (int m = 0; m < 4; ++m)
                #pragma unroll
                for (int n = 0; n < 4; ++n)
                    acc[m][n] = __builtin_amdgcn_mfma_f32_16x16x32_f16(af[m], bf[n], acc[m][n], 0, 0, 0);
        }
        __syncthreads();                      // drains input prefetch (hidden)
        if (cc < 3) {
            stage_w(cc + 1);                  // 36.9KB L2-hot refill
            __syncthreads();
        }
    }

    // ---- epilogue (granule-major stores/res) ----
    const int r4 = kg * 4;
    const int qb = lr * 128 + chf * 64;       // q within tile (+n*16+l15)
    if (GLU) {
        #pragma unroll
        for (int mv = 0; mv < 2; ++mv) {
            const int v0 = cb * 32 + mv * 16 + r4;
            float s1[4], o1[4], s2[4], o2[4];
            #pragma unroll
            for (int r = 0; r < 4; ++r) {
                s1[r] = gamma[v0 + r] * BN_SC;        o1[r] = beta[v0 + r];
                s2[r] = gamma[v0 + r + HALF] * BN_SC; o2[r] = beta[v0 + r + HALF];
            }
            #pragma unroll
            for (int n = 0; n < 4; ++n) {
                const int qc = qb + (n << 4) + l15;
                float ov[4];
                #pragma unroll
                for (int r = 0; r < 4; ++r) {
                    float yv = acc[mv][n][r] * s1[r] + o1[r];
                    float zv = acc[mv + 2][n][r] * s2[r] + o2[r];
                    ov[r] = yv / (1.0f + __expf(-zv));
                }
                f16x4 tv;
                #pragma unroll
                for (int r = 0; r < 4; ++r) tv[r] = (f16)ov[r];
                *(f16x4*)(outh + ((((size_t)b * (OCH / 8) + (v0 >> 3)) << 14)
                                  + q0 + qc) * 8 + (v0 & 7)) = tv;
            }
        }
    } else {
        #pragma unroll
        for (int m = 0; m < 4; ++m) {
            const int c0 = cb * 64 + m * 16 + r4;
            float s[4], o[4];
            #pragma unroll
            for (int r = 0; r < 4; ++r) {
                s[r] = gamma[c0 + r] * BN_SC; o[r] = beta[c0 + r];
            }
            #pragma unroll
            for (int n = 0; n < 4; ++n) {
                const int qc = qb + (n << 4) + l15;
                const size_t gaddr = ((((size_t)b * 16 + (c0 >> 3)) << 14) + q0 + qc) * 8 + (c0 & 7);
                float ov[4];
                #pragma unroll
                for (int r = 0; r < 4; ++r) ov[r] = acc[m][n][r] * s[r] + o[r];
                if (RES) {
                    f16x4 rv = *(const f16x4*)(res + gaddr);
                    #pragma unroll
                    for (int r = 0; r < 4; ++r) ov[r] += (float)rv[r];
                }
                f16x4 tv;
                #pragma unroll
                for (int r = 0; r < 4; ++r) tv[r] = (f16)ov[r];
                *(f16x4*)(outh + gaddr) = tv;
            }
        }
    }
}

// ---------------- UP conv (R13 + XCD pin): barrier-free K-loop --------------
__global__ __launch_bounds__(512, 2) void conv_up_k(
        const f16* __restrict__ in, const f16* __restrict__ wt,
        const float* __restrict__ gamma, const float* __restrict__ beta,
        float* __restrict__ outf, const char* __restrict__ zeros) {
    __shared__ char wL[131072];

    const int tid = threadIdx.x, lane = tid & 63, wv = tid >> 6;
    const int l15 = lane & 15, kg = lane >> 4;
    const int wg = blockIdx.x;
    const int b = wg & 7;
    const int pos = wg >> 3;                  // [0,128)
    const int cb = pos >> 6;
    const int x = pos & 63;
    const int j = x >> 1, ph = x & 1;
    const int rr = wv >> 1;                   // output row 0..3
    const int p  = wv & 1;                    // output col parity

    const char* wtb = (const char*)wt + (size_t)(cb * 2 + ph) * 131072;
    const int dstB = (tid & 448) << 4;
    #pragma unroll
    for (int k = 0; k < 16; ++k)
        gload16(wtb + (((k << 9) + tid) << 4), wL + (k << 13) + dstB);
    __syncthreads();

    f32x4 acc[4][8];
    #pragma unroll
    for (int m = 0; m < 4; ++m)
        #pragma unroll
        for (int n = 0; n < 8; ++n) acc[m][n] = (f32x4){0.f, 0.f, 0.f, 0.f};

    const char* inbB = (const char*)in + (size_t)b * QN * 256;  // 16 planes
    const int colb = (l15 + p - 1) << 4;
    const char* rp0;
    const char* rp1;
    {
        int r0 = 4 * j - 1 + ph + rr;
        int r1 = r0 + 1;
        rp0 = ((unsigned)r0 < 128u)
            ? inbB + (((size_t)kg * QN + (size_t)r0 * 128) << 4) + colb
            : zeros + 16 + colb;
        rp1 = ((unsigned)r1 < 128u)
            ? inbB + (((size_t)kg * QN + (size_t)r1 * 128) << 4) + colb
            : zeros + 16 + colb;
    }

    auto LG = [&](f16x8 (&bf)[8], int cc, int t) {
        const int sh_ = t & 1;
        const char* bl = ((t >> 1) ? rp1 : rp0) + (cc << 20) + (sh_ << 4);
        #pragma unroll
        for (int n = 0; n < 8; ++n) {
            if (n == 0 || n == 7) {
                int sc = (n << 4) + l15 + sh_ + p - 1;
                const char* a = ((unsigned)sc < 128u)
                    ? (bl + n * 256)
                    : (zeros + (cc << 20) + 16 + sc * 16);
                bf[n] = *(const f16x8*)a;
            } else {
                bf[n] = *(const f16x8*)(bl + n * 256);
            }
        }
    };
    auto CP = [&](f16x8 (&bf)[8], int cc, int t) {
        f16x8 af[4];
        const int tb = cc * 32768 + ((p * 4 + t) << 12);
        #pragma unroll
        for (int m = 0; m < 4; ++m) {
            int co = m * 16 + l15;
            af[m] = *(const f16x8*)(wL + tb + (co << 6)
                                    + ((kg ^ ((co >> 1) & 3)) << 4));
        }
        #pragma unroll
        for (int m = 0; m < 4; ++m)
            #pragma unroll
            for (int n = 0; n < 8; ++n)
                acc[m][n] = __builtin_amdgcn_mfma_f32_16x16x32_f16(af[m], bf[n], acc[m][n], 0, 0, 0);
    };

    f16x8 bfA[8], bfB[8];
    LG(bfA, 0, 0);
    #pragma unroll
    for (int k = 0; k < 16; ++k) {
        const int cc = k >> 2, t = k & 3;
        const int k1 = k + 1;
        if ((k & 1) == 0) {
            if (k1 < 16) LG(bfB, k1 >> 2, k1 & 3);
            CP(bfA, cc, t);
        } else {
            if (k1 < 16) LG(bfA, k1 >> 2, k1 & 3);
            CP(bfB, cc, t);
        }
    }

    // ---- epilogue: BN + GLU -> fp32 NCHW ----
    const int r4 = kg * 4;
    const int h = 8 * j + 2 * rr + ph;
    #pragma unroll
    for (int mv = 0; mv < 2; ++mv) {
        const int v0 = cb * 32 + mv * 16 + r4;
        float s1[4], o1[4], s2[4], o2[4];
        #pragma unroll
        for (int r = 0; r < 4; ++r) {
            s1[r] = gamma[v0 + r] * BN_SC;      o1[r] = beta[v0 + r];
            s2[r] = gamma[v0 + r + 64] * BN_SC; o2[r] = beta[v0 + r + 64];
        }
        #pragma unroll
        for (int n = 0; n < 8; ++n) {
            const int w = 2 * ((n << 4) + l15) + p;
            float ov[4];
            #pragma unroll
            for (int r = 0; r < 4; ++r) {
                float yv = acc[mv][n][r] * s1[r] + o1[r];
                float zv = acc[mv + 2][n][r] * s2[r] + o2[r];
                ov[r] = yv / (1.0f + __expf(-zv));
            }
            #pragma unroll
            for (int r = 0; r < 4; ++r)
                outf[(((size_t)b * 64 + v0 + r) * 256 + h) * 256 + w] = ov[r];
        }
    }
}

// ---------------------------------------------------------------------------
extern "C" void kernel_launch(void* const* d_in, const int* in_sizes, int n_in,
                              void* d_out, int out_size, void* d_ws, size_t ws_size,
                              hipStream_t stream) {
    (void)in_sizes; (void)n_in; (void)out_size; (void)ws_size;
    const float* h_code    = (const float*)d_in[0];
    const float* word_embs = (const float*)d_in[2];
    const void*  mask      = d_in[3];
    const float* w_ctx     = (const float*)d_in[4];
    const float* r0_w1 = (const float*)d_in[5];
    const float* r0_g1 = (const float*)d_in[6];
    const float* r0_b1 = (const float*)d_in[7];
    const float* r0_w2 = (const float*)d_in[8];
    const float* r0_g2 = (const float*)d_in[9];
    const float* r0_b2 = (const float*)d_in[10];
    const float* r1_w1 = (const float*)d_in[11];
    const float* r1_g1 = (const float*)d_in[12];
    const float* r1_b1 = (const float*)d_in[13];
    const float* r1_w2 = (const float*)d_in[14];
    const float* r1_g2 = (const float*)d_in[15];
    const float* r1_b2 = (const float*)d_in[16];
    const float* up_w  = (const float*)d_in[17];
    const float* up_g  = (const float*)d_in[18];
    const float* up_b  = (const float*)d_in[19];

    float* outp = (float*)d_out;                         // (8,64,256,256) fp32
    float* attp = outp + (size_t)B_N * NGF * 4 * HC * WC;

    unsigned* mbits = (unsigned*)d_ws;
    float* sT  = (float*)((char*)d_ws + 1024);
    char* zeros = (char*)d_ws + ((size_t)4 << 20);                 // 4x4KB stripes
    f16* hcA   = (f16*)((char*)d_ws + ((size_t)8 << 20));          // 32MB
    f16* wtbuf = (f16*)((char*)d_ws + ((size_t)40 << 20));         // ~3MB

    const int W1_TOT = 4 * 4 * 9 * 64 * 32;   // 294912 (GLU 256-out)
    const int W2_TOT = 2 * 4 * 9 * 64 * 32;   // 147456
    const int WUP_TOT = 2 * 2 * 4 * 2 * 4 * 64 * 32;   // 524288 (parity 2x2)
    f16* Wr0c1 = wtbuf;
    f16* Wr0c2 = Wr0c1 + W1_TOT;
    f16* Wr1c1 = Wr0c2 + W2_TOT;
    f16* Wr1c2 = Wr1c1 + W1_TOT;
    f16* Wup   = Wr1c2 + W2_TOT;

    f16* Bbuf = (f16*)d_out;                               // [0,32MB)
    f16* Cbuf = (f16*)((char*)d_out + ((size_t)32 << 20)); // [32,64MB)

    prep_mask_k<<<1, 256, 0, stream>>>(mask, mbits, (unsigned*)zeros);
    source_t_k<<<64, 256, 0, stream>>>(w_ctx, word_embs, sT);

    wt_transform_k<<<(W1_TOT + 255) / 256, 256, 0, stream>>>(r0_w1, Wr0c1, W1_TOT, 128);
    wt_transform_k<<<(W2_TOT + 255) / 256, 256, 0, stream>>>(r0_w2, Wr0c2, W2_TOT, 0);
    wt_transform_k<<<(W1_TOT + 255) / 256, 256, 0, stream>>>(r1_w1, Wr1c1, W1_TOT, 128);
    wt_transform_k<<<(W2_TOT + 255) / 256, 256, 0, stream>>>(r1_w2, Wr1c2, W2_TOT, 0);
    wt_up_transform_k<<<WUP_TOT / 256, 256, 0, stream>>>(up_w, Wup);

    attention_k<<<B_N * QN / 256, 256, 0, stream>>>(h_code, sT, mbits, attp, hcA);

    // r0: conv1+GLU (hcA->B), conv2+res hcA (B->C)   [1D grids, b = wg&7]
    conv_mfma_k<256, true,  false>
        <<<1024, 512, 0, stream>>>(hcA, Wr0c1, r0_g1, r0_b1, nullptr, Bbuf, zeros);
    conv_mfma_k<128, false, true>
        <<<512, 512, 0, stream>>>(Bbuf, Wr0c2, r0_g2, r0_b2, hcA, Cbuf, zeros);
    // r1: conv1+GLU (C->B), conv2+res C (B->hcA)
    conv_mfma_k<256, true,  false>
        <<<1024, 512, 0, stream>>>(Cbuf, Wr1c1, r1_g1, r1_b1, nullptr, Bbuf, zeros);
    conv_mfma_k<128, false, true>
        <<<512, 512, 0, stream>>>(Bbuf, Wr1c2, r1_g2, r1_b2, Cbuf, hcA, zeros);
    // upsample2x + conv + GLU -> final fp32 NCHW (barrier-free, XCD-pinned)
    conv_up_k<<<1024, 512, 0, stream>>>(hcA, Wup, up_g, up_b, outp, zeros);
}

// Round 16
// 416.354 us; speedup vs baseline: 1.0413x; 1.0056x over previous
//
#include <hip/hip_runtime.h>
#include <math.h>

// ---------------------------------------------------------------------------
// R16: non-UP convs -> 32x32x16 MFMA with CONFLICT-FREE fragment-linear
// layouts (R14's shape was right, its bank pattern wrong). Weights:
// [cb][cc][t][gran4][co64]*16B (af = t*4096+gran*1024+co*16, lanes consecutive
// 16B). Input LDS: [rowgran24][wi132]*16B, linear staging map (no XOR).
// Balance: LDS 4608cy ~= MFMA 4648cy per CU per cc (was 11520 vs 5590).
// XCD pin reverted (R15: FETCH 26.7->68MB, hurt). conv_up = R13 barrier-free.
// ws: [0]mbits | [1KB]sT | [4MB)zeros(4x4KB stripes at MBs) | [8MB)hcA | [40MB)wt
// ---------------------------------------------------------------------------

#define B_N 8
#define NGF 64
#define HC 128
#define WC 128
#define QN (HC*WC)        // 16384
#define NEF 256
#define SN 32
#define TEMP_INV (1.0f/0.7f)
#define BN_SC 0.99999500003749969f   // 1/sqrt(1+1e-5)
#define TOPK 24

typedef _Float16 f16;
typedef __attribute__((ext_vector_type(8))) _Float16 f16x8;
typedef __attribute__((ext_vector_type(4))) _Float16 f16x4;
typedef __attribute__((ext_vector_type(4))) float f32x4;
typedef __attribute__((ext_vector_type(16))) float f32x16;

__device__ __forceinline__ void gload16(const void* g, void* l) {
    __builtin_amdgcn_global_load_lds(
        (const __attribute__((address_space(1))) void*)g,
        (__attribute__((address_space(3))) void*)l,
        16, 0, 0);
}

// ---------------- mask prep + 4KB zero stripes at +{0..3}MB -----------------
__global__ void prep_mask_k(const void* __restrict__ mraw,
                            unsigned* __restrict__ mbits,
                            unsigned* __restrict__ zp) {
    __shared__ int mode;
    if (threadIdx.x == 0) {
        const unsigned* u = (const unsigned*)mraw;
        bool i32 = true, f32m = true;
        for (int i = 0; i < 64; ++i) {
            unsigned v = u[i];
            if (v > 1u) i32 = false;
            if (v != 0u && v != 0x3F800000u) f32m = false;
        }
        mode = i32 ? 0 : (f32m ? 1 : 2);
    }
    __syncthreads();
    int t = threadIdx.x;
    for (int i = t; i < 4 * 1056; i += 256) {
        int cc = i / 1056, w = i - cc * 1056;
        zp[cc * 262144 + w - 16] = 0u;
    }
    if (t < B_N) {
        unsigned bits = 0;
        for (int s = 0; s < SN; ++s) {
            int idx = t * SN + s;
            bool on;
            if (mode == 0)      on = ((const int*)mraw)[idx] != 0;
            else if (mode == 1) on = ((const float*)mraw)[idx] != 0.0f;
            else                on = ((const unsigned char*)mraw)[idx] != 0;
            if (on) bits |= (1u << s);
        }
        mbits[t] = bits;
    }
}

// ---------------- sourceT[b,o,s]: 64 blocks, thread=(o_local,s) -------------
__global__ __launch_bounds__(256) void source_t_k(
        const float* __restrict__ w_ctx, const float* __restrict__ word_embs,
        float* __restrict__ sT) {
    int b = blockIdx.x >> 3;
    int o = ((blockIdx.x & 7) << 3) + (threadIdx.x >> 5);
    int s = threadIdx.x & 31;
    const float* wrow = w_ctx + (size_t)o * NEF;
    const float* wb = word_embs + (size_t)b * NEF * SN + s;
    float acc = 0.0f;
    #pragma unroll 8
    for (int c = 0; c < NEF; ++c) acc += wrow[c] * wb[(size_t)c * SN];
    sT[((size_t)b * NGF + o) * SN + s] = acc;
}

// ---------------- attention: writes h_c granule-major NCHW8c ----------------
__global__ __launch_bounds__(256) void attention_k(
        const float* __restrict__ h_code, const float* __restrict__ sT,
        const unsigned* __restrict__ mbits,
        float* __restrict__ att_out,   // (B,S,Q) fp32
        f16* __restrict__ hc) {        // [b][16][QN][8]: g0..7 h, g8..15 wctx
    int r0 = blockIdx.x * 256;
    int b = r0 >> 14;
    __shared__ float st[NGF * SN];
    const float* stg = sT + (size_t)b * NGF * SN;
    for (int i = threadIdx.x; i < NGF * SN; i += 256) st[i] = stg[i];
    __syncthreads();
    int q = (r0 & (QN - 1)) + threadIdx.x;

    const float* hb = h_code + (size_t)b * NGF * QN + q;
    f16* hcb = hc + (size_t)b * QN * 128;

    float a[SN];
    #pragma unroll
    for (int s = 0; s < SN; ++s) a[s] = 0.0f;
    for (int g8 = 0; g8 < 8; ++g8) {
        f16x8 t;
        #pragma unroll
        for (int r = 0; r < 8; ++r) {
            float v = hb[(size_t)(g8 * 8 + r) * QN];
            t[r] = (f16)v;
            #pragma unroll
            for (int s = 0; s < SN; ++s) a[s] += v * st[(g8 * 8 + r) * SN + s];
        }
        *(f16x8*)(hcb + ((size_t)g8 * QN + q) * 8) = t;   // contiguous 16B/lane
    }
    unsigned mb = mbits[q & 7];       // reference tile quirk: mask row = q%8
    #pragma unroll
    for (int s = 0; s < SN; ++s)
        a[s] = ((mb >> s) & 1u) ? -INFINITY : a[s] * TEMP_INV;

    // top-k threshold via stable rank (24th largest incl. duplicates).
    float thr = -INFINITY;
    #pragma unroll
    for (int s = 0; s < SN; ++s) {
        int rank = 0;
        #pragma unroll
        for (int j = 0; j < SN; ++j)
            rank += (a[j] > a[s]) || (a[j] == a[s] && j < s);
        if (rank == TOPK - 1) thr = a[s];
    }
    float m = -INFINITY;
    #pragma unroll
    for (int s = 0; s < SN; ++s) {
        if (a[s] < thr) a[s] = -INFINITY;
        m = fmaxf(m, a[s]);
    }
    float p[SN];
    if (m == -INFINITY) {
        #pragma unroll
        for (int s = 0; s < SN; ++s) p[s] = 1.0f / SN;
    } else {
        float sum = 0.0f;
        #pragma unroll
        for (int s = 0; s < SN; ++s) { p[s] = __expf(a[s] - m); sum += p[s]; }
        float inv = 1.0f / sum;
        #pragma unroll
        for (int s = 0; s < SN; ++s) p[s] *= inv;
    }
    float* ao = att_out + (size_t)b * SN * QN + q;
    #pragma unroll
    for (int s = 0; s < SN; ++s) ao[(size_t)s * QN] = p[s];
    for (int g8 = 0; g8 < 8; ++g8) {
        f16x8 t;
        #pragma unroll
        for (int r = 0; r < 8; ++r) {
            float acc = 0.0f;
            #pragma unroll
            for (int s = 0; s < SN; ++s) acc += st[(g8 * 8 + r) * SN + s] * p[s];
            t[r] = (f16)acc;
        }
        *(f16x8*)(hcb + ((size_t)(8 + g8) * QN + q) * 8) = t;
    }
}

// ---------------- weight transform: OIHW fp32 -> [cb][cc][t][gran][co] f16 --
// fragment-linear: af lane reads (gran, co=m*32+l31) at gran*1024 + co*16.
__global__ __launch_bounds__(256) void wt_transform_k(
        const float* __restrict__ w, f16* __restrict__ wt,
        int total, int HALF /*0 = non-GLU*/) {
    int idx = blockIdx.x * 256 + threadIdx.x;
    if (idx >= total) return;
    int e    = idx & 7;
    int cop  = (idx >> 3) & 63;
    int gran = (idx >> 9) & 3;
    int u    = idx >> 11;
    int t    = u % 9;
    int v    = u / 9;
    int cc   = v & 3;
    int cb   = v >> 2;
    int ci   = cc * 32 + gran * 8 + e;
    int co   = HALF ? (cop < 32 ? cb * 32 + cop : HALF + cb * 32 + (cop - 32))
                    : cb * 64 + cop;
    wt[idx] = (f16)w[((size_t)co * 128 + ci) * 9 + t];
}

// ---------------- UP weight transform: parity-collapsed 2x2 kernels --------
// (16x16 layout with XOR swizzle, unchanged — conv_up still uses 16x16)
__global__ __launch_bounds__(256) void wt_up_transform_k(
        const float* __restrict__ w, f16* __restrict__ wt) {
    int idx = blockIdx.x * 256 + threadIdx.x;    // total 524288
    int e   = idx & 7;
    int gp  = (idx >> 3) & 3;
    int cop = (idx >> 5) & 63;
    int tap = (idx >> 11) & 3;
    int pw  = (idx >> 13) & 1;
    int cc  = (idx >> 14) & 3;
    int ph  = (idx >> 16) & 1;
    int cb  = (idx >> 17) & 1;
    int g   = gp ^ ((cop >> 1) & 3);
    int ci  = cc * 32 + g * 8 + e;
    int co  = cop < 32 ? cb * 32 + cop : 64 + cb * 32 + (cop - 32);
    int ra = tap >> 1, bb = tap & 1;
    const float* wp = w + ((size_t)co * 128 + ci) * 9;
    float acc = 0.0f;
    #pragma unroll
    for (int kh = 0; kh < 3; ++kh) {
        int rma = (ph == 0) ? (kh == 0 ? 0 : 1) : (kh == 2 ? 1 : 0);
        if (rma != ra) continue;
        #pragma unroll
        for (int kw = 0; kw < 3; ++kw) {
            int cma = (pw == 0) ? (kw == 0 ? 0 : 1) : (kw == 2 ? 1 : 0);
            if (cma == bb) acc += wp[kh * 3 + kw];
        }
    }
    wt[idx] = (f16)acc;
}

// ---------------- non-UP conv3x3: 512 thr, q-512, 32x32x16, conflict-free ---
// Input LDS [rowgran24][wi132]*16B, weights [t][gran][co]*16B — all fragment
// reads are consecutive-lane-consecutive-16B (no XOR, no conflicts).
template<int COUT, bool GLU, bool RES>
__global__ __launch_bounds__(512) void conv_mfma_k(
        const f16* __restrict__ in, const f16* __restrict__ wt,
        const float* __restrict__ gamma, const float* __restrict__ beta,
        const f16* __restrict__ res, f16* __restrict__ outh,
        const char* __restrict__ zeros) {
    constexpr int HALF = COUT / 2;
    constexpr int OCH  = GLU ? HALF : COUT;
    constexpr int IBUF = 50688;               // 24 rowgran x 132 wi x 16B

    __shared__ char smem[2 * IBUF + 36864];
    char* wB = smem + 2 * IBUF;

    const int tid = threadIdx.x, lane = tid & 63, wv = tid >> 6;
    const int l31 = lane & 31, lg = lane >> 5;
    const int b = blockIdx.z, cb = blockIdx.y, qt = blockIdx.x;
    const int q0 = qt * 512;
    const int h0 = qt * 4;
    const int lr = wv >> 1, chf = wv & 1;

    f32x16 acc[2][2];
    #pragma unroll
    for (int m = 0; m < 2; ++m)
        #pragma unroll
        for (int n = 0; n < 2; ++n)
            #pragma unroll
            for (int r = 0; r < 16; ++r) acc[m][n][r] = 0.0f;

    const f16* inb = in + (size_t)b * QN * 128;
    const char* wtb = (const char*)wt + (size_t)cb * 147456;

    // hoisted staging sources: idx -> (rg = idx/132, wi = idx%132);
    // r = rg>>2, gran = rg&3; src plane = gran (+cc*1MB per cc).
    const char* srcK[7];
    #pragma unroll
    for (int k = 0; k < 7; ++k) {
        int idx = (k << 9) + tid;             // k==6: only tid<96 used
        int rg = idx / 132;
        int wi = idx - rg * 132;
        int r = rg >> 2, gran = rg & 3;
        int gh = h0 - 1 + r;
        int gw = wi - 1;
        const char* s = zeros;
        if (wi < 130 && (unsigned)gh < (unsigned)HC && (unsigned)gw < (unsigned)WC)
            s = (const char*)(inb + (((size_t)gran * QN + (size_t)gh * WC + gw) << 3));
        srcK[k] = s;
    }
    const int dstB = (tid & 448) << 4;

    auto stage_in = [&](int cc, int buf) {
        char* base = smem + buf * IBUF;
        #pragma unroll
        for (int k = 0; k < 6; ++k)
            gload16(srcK[k] + (cc << 20), base + (k << 13) + dstB);
        if (tid < 96)
            gload16(srcK[6] + (cc << 20), base + (6 << 13) + dstB);
    };
    auto stage_w = [&](int cc) {
        const char* wsrc = wtb + cc * 36864 + (tid << 4);
        #pragma unroll
        for (int k = 0; k < 4; ++k)
            gload16(wsrc + (k << 13), wB + (k << 13) + dstB);
        if (tid < 256)
            gload16(wsrc + (4 << 13), wB + (4 << 13) + dstB);
    };

    stage_in(0, 0);
    stage_w(0);
    __syncthreads();
    for (int cc = 0; cc < 4; ++cc) {
        if (cc < 3) stage_in(cc + 1, (cc + 1) & 1);   // hides under compute
        const char* bb = smem + (cc & 1) * IBUF;

        #pragma unroll
        for (int t = 0; t < 9; ++t) {
            const int kh = t / 3, kw = t % 3;
            f16x8 af[2][2], bf[2][2];          // [kk][tile]
            #pragma unroll
            for (int kk = 0; kk < 2; ++kk) {
                const int gran = kk * 2 + lg;
                #pragma unroll
                for (int m = 0; m < 2; ++m) {
                    int co = m * 32 + l31;
                    af[kk][m] = *(const f16x8*)(wB + (t << 12) + (gran << 10)
                                                + (co << 4));
                }
                #pragma unroll
                for (int n = 0; n < 2; ++n) {
                    int wi = chf * 64 + n * 32 + l31 + kw;
                    int rg = (lr + kh) * 4 + gran;
                    bf[kk][n] = *(const f16x8*)(bb + (rg * 132 + wi) * 16);
                }
            }
            #pragma unroll
            for (int kk = 0; kk < 2; ++kk)
                #pragma unroll
                for (int m = 0; m < 2; ++m)
                    #pragma unroll
                    for (int n = 0; n < 2; ++n)
                        acc[m][n] = __builtin_amdgcn_mfma_f32_32x32x16_f16(
                            af[kk][m], bf[kk][n], acc[m][n], 0, 0, 0);
        }
        __syncthreads();                      // drains input prefetch (hidden)
        if (cc < 3) {
            stage_w(cc + 1);                  // 36.9KB L2-hot refill
            __syncthreads();
        }
    }

    // ---- epilogue: C/D col=l31 (q), row=(reg&3)+8*(reg>>2)+4*lg (co) ------
    // (verified in R14: absmax unchanged)
    const int qb = lr * 128 + chf * 64;
    if (GLU) {
        #pragma unroll
        for (int n = 0; n < 2; ++n) {
            const int q = q0 + qb + n * 32 + l31;
            #pragma unroll
            for (int rg = 0; rg < 4; ++rg) {
                const int co = cb * 32 + rg * 8 + 4 * lg;   // value channel base
                float s1[4], o1[4], s2[4], o2[4];
                #pragma unroll
                for (int r = 0; r < 4; ++r) {
                    s1[r] = gamma[co + r] * BN_SC;        o1[r] = beta[co + r];
                    s2[r] = gamma[co + r + HALF] * BN_SC; o2[r] = beta[co + r + HALF];
                }
                f16x4 tv;
                #pragma unroll
                for (int r = 0; r < 4; ++r) {
                    float yv = acc[0][n][rg * 4 + r] * s1[r] + o1[r];
                    float zv = acc[1][n][rg * 4 + r] * s2[r] + o2[r];
                    tv[r] = (f16)(yv / (1.0f + __expf(-zv)));
                }
                *(f16x4*)(outh + ((((size_t)b * (OCH / 8) + (co >> 3)) << 14)
                                  + q) * 8 + (co & 7)) = tv;
            }
        }
    } else {
        #pragma unroll
        for (int m = 0; m < 2; ++m) {
            #pragma unroll
            for (int n = 0; n < 2; ++n) {
                const int q = q0 + qb + n * 32 + l31;
                #pragma unroll
                for (int rg = 0; rg < 4; ++rg) {
                    const int c0 = cb * 64 + m * 32 + rg * 8 + 4 * lg;
                    const size_t gaddr = ((((size_t)b * 16 + (c0 >> 3)) << 14) + q) * 8 + (c0 & 7);
                    float s[4], o[4], ov[4];
                    #pragma unroll
                    for (int r = 0; r < 4; ++r) {
                        s[r] = gamma[c0 + r] * BN_SC; o[r] = beta[c0 + r];
                        ov[r] = acc[m][n][rg * 4 + r] * s[r] + o[r];
                    }
                    if (RES) {
                        f16x4 rv = *(const f16x4*)(res + gaddr);
                        #pragma unroll
                        for (int r = 0; r < 4; ++r) ov[r] += (float)rv[r];
                    }
                    f16x4 tv;
                    #pragma unroll
                    for (int r = 0; r < 4; ++r) tv[r] = (f16)ov[r];
                    *(f16x4*)(outh + gaddr) = tv;
                }
            }
        }
    }
}

// ---------------- UP conv (R13): barrier-free K-loop, bf direct glb->VGPR ---
__global__ __launch_bounds__(512, 2) void conv_up_k(
        const f16* __restrict__ in, const f16* __restrict__ wt,
        const float* __restrict__ gamma, const float* __restrict__ beta,
        float* __restrict__ outf, const char* __restrict__ zeros) {
    __shared__ char wL[131072];

    const int tid = threadIdx.x, lane = tid & 63, wv = tid >> 6;
    const int l15 = lane & 15, kg = lane >> 4;
    const int b = blockIdx.z, cb = blockIdx.y;
    const int j = blockIdx.x >> 1, ph = blockIdx.x & 1;
    const int rr = wv >> 1;                   // output row 0..3
    const int p  = wv & 1;                    // output col parity

    const char* wtb = (const char*)wt + (size_t)(cb * 2 + ph) * 131072;
    const int dstB = (tid & 448) << 4;
    #pragma unroll
    for (int k = 0; k < 16; ++k)
        gload16(wtb + (((k << 9) + tid) << 4), wL + (k << 13) + dstB);
    __syncthreads();

    f32x4 acc[4][8];
    #pragma unroll
    for (int m = 0; m < 4; ++m)
        #pragma unroll
        for (int n = 0; n < 8; ++n) acc[m][n] = (f32x4){0.f, 0.f, 0.f, 0.f};

    const char* inbB = (const char*)in + (size_t)b * QN * 256;  // 16 planes
    const int colb = (l15 + p - 1) << 4;
    const char* rp0;
    const char* rp1;
    {
        int r0 = 4 * j - 1 + ph + rr;
        int r1 = r0 + 1;
        rp0 = ((unsigned)r0 < 128u)
            ? inbB + (((size_t)kg * QN + (size_t)r0 * 128) << 4) + colb
            : zeros + 16 + colb;
        rp1 = ((unsigned)r1 < 128u)
            ? inbB + (((size_t)kg * QN + (size_t)r1 * 128) << 4) + colb
            : zeros + 16 + colb;
    }

    auto LG = [&](f16x8 (&bf)[8], int cc, int t) {
        const int sh_ = t & 1;
        const char* bl = ((t >> 1) ? rp1 : rp0) + (cc << 20) + (sh_ << 4);
        #pragma unroll
        for (int n = 0; n < 8; ++n) {
            if (n == 0 || n == 7) {
                int sc = (n << 4) + l15 + sh_ + p - 1;
                const char* a = ((unsigned)sc < 128u)
                    ? (bl + n * 256)
                    : (zeros + (cc << 20) + 16 + sc * 16);
                bf[n] = *(const f16x8*)a;
            } else {
                bf[n] = *(const f16x8*)(bl + n * 256);
            }
        }
    };
    auto CP = [&](f16x8 (&bf)[8], int cc, int t) {
        f16x8 af[4];
        const int tb = cc * 32768 + ((p * 4 + t) << 12);
        #pragma unroll
        for (int m = 0; m < 4; ++m) {
            int co = m * 16 + l15;
            af[m] = *(const f16x8*)(wL + tb + (co << 6)
                                    + ((kg ^ ((co >> 1) & 3)) << 4));
        }
        #pragma unroll
        for (int m = 0; m < 4; ++m)
            #pragma unroll
            for (int n = 0; n < 8; ++n)
                acc[m][n] = __builtin_amdgcn_mfma_f32_16x16x32_f16(af[m], bf[n], acc[m][n], 0, 0, 0);
    };

    f16x8 bfA[8], bfB[8];
    LG(bfA, 0, 0);
    #pragma unroll
    for (int k = 0; k < 16; ++k) {
        const int cc = k >> 2, t = k & 3;
        const int k1 = k + 1;
        if ((k & 1) == 0) {
            if (k1 < 16) LG(bfB, k1 >> 2, k1 & 3);
            CP(bfA, cc, t);
        } else {
            if (k1 < 16) LG(bfA, k1 >> 2, k1 & 3);
            CP(bfB, cc, t);
        }
    }

    // ---- epilogue: BN + GLU -> fp32 NCHW ----
    const int r4 = kg * 4;
    const int h = 8 * j + 2 * rr + ph;
    #pragma unroll
    for (int mv = 0; mv < 2; ++mv) {
        const int v0 = cb * 32 + mv * 16 + r4;
        float s1[4], o1[4], s2[4], o2[4];
        #pragma unroll
        for (int r = 0; r < 4; ++r) {
            s1[r] = gamma[v0 + r] * BN_SC;      o1[r] = beta[v0 + r];
            s2[r] = gamma[v0 + r + 64] * BN_SC; o2[r] = beta[v0 + r + 64];
        }
        #pragma unroll
        for (int n = 0; n < 8; ++n) {
            const int w = 2 * ((n << 4) + l15) + p;
            float ov[4];
            #pragma unroll
            for (int r = 0; r < 4; ++r) {
                float yv = acc[mv][n][r] * s1[r] + o1[r];
                float zv = acc[mv + 2][n][r] * s2[r] + o2[r];
                ov[r] = yv / (1.0f + __expf(-zv));
            }
            #pragma unroll
            for (int r = 0; r < 4; ++r)
                outf[(((size_t)b * 64 + v0 + r) * 256 + h) * 256 + w] = ov[r];
        }
    }
}

// ---------------------------------------------------------------------------
extern "C" void kernel_launch(void* const* d_in, const int* in_sizes, int n_in,
                              void* d_out, int out_size, void* d_ws, size_t ws_size,
                              hipStream_t stream) {
    (void)in_sizes; (void)n_in; (void)out_size; (void)ws_size;
    const float* h_code    = (const float*)d_in[0];
    const float* word_embs = (const float*)d_in[2];
    const void*  mask      = d_in[3];
    const float* w_ctx     = (const float*)d_in[4];
    const float* r0_w1 = (const float*)d_in[5];
    const float* r0_g1 = (const float*)d_in[6];
    const float* r0_b1 = (const float*)d_in[7];
    const float* r0_w2 = (const float*)d_in[8];
    const float* r0_g2 = (const float*)d_in[9];
    const float* r0_b2 = (const float*)d_in[10];
    const float* r1_w1 = (const float*)d_in[11];
    const float* r1_g1 = (const float*)d_in[12];
    const float* r1_b1 = (const float*)d_in[13];
    const float* r1_w2 = (const float*)d_in[14];
    const float* r1_g2 = (const float*)d_in[15];
    const float* r1_b2 = (const float*)d_in[16];
    const float* up_w  = (const float*)d_in[17];
    const float* up_g  = (const float*)d_in[18];
    const float* up_b  = (const float*)d_in[19];

    float* outp = (float*)d_out;                         // (8,64,256,256) fp32
    float* attp = outp + (size_t)B_N * NGF * 4 * HC * WC;

    unsigned* mbits = (unsigned*)d_ws;
    float* sT  = (float*)((char*)d_ws + 1024);
    char* zeros = (char*)d_ws + ((size_t)4 << 20);                 // 4x4KB stripes
    f16* hcA   = (f16*)((char*)d_ws + ((size_t)8 << 20));          // 32MB
    f16* wtbuf = (f16*)((char*)d_ws + ((size_t)40 << 20));         // ~3MB

    const int W1_TOT = 4 * 4 * 9 * 64 * 32;   // 294912 (GLU 256-out)
    const int W2_TOT = 2 * 4 * 9 * 64 * 32;   // 147456
    const int WUP_TOT = 2 * 2 * 4 * 2 * 4 * 64 * 32;   // 524288 (parity 2x2)
    f16* Wr0c1 = wtbuf;
    f16* Wr0c2 = Wr0c1 + W1_TOT;
    f16* Wr1c1 = Wr0c2 + W2_TOT;
    f16* Wr1c2 = Wr1c1 + W1_TOT;
    f16* Wup   = Wr1c2 + W2_TOT;

    f16* Bbuf = (f16*)d_out;                               // [0,32MB)
    f16* Cbuf = (f16*)((char*)d_out + ((size_t)32 << 20)); // [32,64MB)

    prep_mask_k<<<1, 256, 0, stream>>>(mask, mbits, (unsigned*)zeros);
    source_t_k<<<64, 256, 0, stream>>>(w_ctx, word_embs, sT);

    wt_transform_k<<<(W1_TOT + 255) / 256, 256, 0, stream>>>(r0_w1, Wr0c1, W1_TOT, 128);
    wt_transform_k<<<(W2_TOT + 255) / 256, 256, 0, stream>>>(r0_w2, Wr0c2, W2_TOT, 0);
    wt_transform_k<<<(W1_TOT + 255) / 256, 256, 0, stream>>>(r1_w1, Wr1c1, W1_TOT, 128);
    wt_transform_k<<<(W2_TOT + 255) / 256, 256, 0, stream>>>(r1_w2, Wr1c2, W2_TOT, 0);
    wt_up_transform_k<<<WUP_TOT / 256, 256, 0, stream>>>(up_w, Wup);

    attention_k<<<(B_N * QN) / 256, 256, 0, stream>>>(h_code, sT, mbits, attp, hcA);

    // r0: conv1+GLU (hcA->B), conv2+res hcA (B->C)
    conv_mfma_k<256, true,  false>
        <<<dim3(32, 4, B_N), 512, 0, stream>>>(hcA, Wr0c1, r0_g1, r0_b1, nullptr, Bbuf, zeros);
    conv_mfma_k<128, false, true>
        <<<dim3(32, 2, B_N), 512, 0, stream>>>(Bbuf, Wr0c2, r0_g2, r0_b2, hcA, Cbuf, zeros);
    // r1: conv1+GLU (C->B), conv2+res C (B->hcA)
    conv_mfma_k<256, true,  false>
        <<<dim3(32, 4, B_N), 512, 0, stream>>>(Cbuf, Wr1c1, r1_g1, r1_b1, nullptr, Bbuf, zeros);
    conv_mfma_k<128, false, true>
        <<<dim3(32, 2, B_N), 512, 0, stream>>>(Bbuf, Wr1c2, r1_g2, r1_b2, Cbuf, hcA, zeros);
    // upsample2x + conv + GLU -> final fp32 NCHW (R13 barrier-free)
    conv_up_k<<<dim3(64, 2, B_N), 512, 0, stream>>>(hcA, Wup, up_g, up_b, outp, zeros);
}